// Round 13
// baseline (5499.089 us; speedup 1.0000x reference)
//
#include <hip/hip_runtime.h>

// KNNGraph bruteforce-blas, euclidean, k=16, include self.
// x: (N=4, M=8192, D=64) fp32. Output: int32 src[N*M*K] then dst[N*M*K].
//
// VALIDATED reference model (R9, absmax=0 — numerics FROZEN):
//   x2  = np.sum(x*x,-1): squares rounded per-element, FLOAT_pairwise_sum
//         n=64 NPY_SIMD path: 4 vec accs (vstep=4), serial blocks,
//         combine (r0+r1)+(r2+r3), double-hadd (S0+S1)+(S2+S3).
//   dot = np.einsum baseline-SSE: per-16 block REVERSED muladd chain
//         v_l = p0l+(p1l+(p2l+(p3l+v_l))), double-hadd (v0+v1)+(v2+v3).
//   d2  = fl(fl(x2j+x2c) - fl(2*dot)); stable ties by lower index.
//
// R13: Q=2 query register blocking. R12 was VALU/LDS co-bound (88% VALU,
// 192 LDS-cyc/visit). Each thread now owns TWO query rows; every candidate
// float4 read from LDS feeds both dots -> wave-candidate visits halve.
// P=4 -> 8 keeps 2048 waves (2/SIMD). Select stays R12's explicit-scalar
// branchless bubble (the 5x win).

#define MM 8192
#define NN 4
#define DD 64
#define KK 16
#define TK 20            // stage-A keep per chunk (16 + 4 safety margin)
#define TILE 64          // candidate tile rows staged in LDS
#define NROWS (NN * MM)  // 32768

// numpy SIMD pairwise sum of squares (SSE baseline), n=64. FROZEN.
__global__ __launch_bounds__(256) void norms_np_kernel(
    const float* __restrict__ x, float* __restrict__ x2) {
#pragma clang fp contract(off)
  int r = blockIdx.x * 256 + threadIdx.x;
  if (r >= NROWS) return;
  const float4* p = (const float4*)(x + (size_t)r * DD);
  float s[DD];
#pragma unroll
  for (int i = 0; i < DD / 4; ++i) {
    float4 v = p[i];
    s[4 * i + 0] = v.x * v.x;
    s[4 * i + 1] = v.y * v.y;
    s[4 * i + 2] = v.z * v.z;
    s[4 * i + 3] = v.w * v.w;
  }
  float acc[4][4];
#pragma unroll
  for (int c = 0; c < 4; ++c)
#pragma unroll
    for (int l = 0; l < 4; ++l) acc[c][l] = s[4 * c + l];
#pragma unroll
  for (int b = 1; b < 4; ++b)
#pragma unroll
    for (int c = 0; c < 4; ++c)
#pragma unroll
      for (int l = 0; l < 4; ++l)
        acc[c][l] = acc[c][l] + s[16 * b + 4 * c + l];
  float S[4];
#pragma unroll
  for (int l = 0; l < 4; ++l)
    S[l] = (acc[0][l] + acc[1][l]) + (acc[2][l] + acc[3][l]);
  x2[r] = (S[0] + S[1]) + (S[2] + S[3]);
}

// dual-query dot accumulate on one shared candidate float4
#define DOT4W(QA, QB, W)                 \
  do {                                   \
    a0 = fmaf((QA).x, (W).x, a0);        \
    a1 = fmaf((QA).y, (W).y, a1);        \
    a2 = fmaf((QA).z, (W).z, a2);        \
    a3 = fmaf((QA).w, (W).w, a3);        \
    b0 = fmaf((QB).x, (W).x, b0);        \
    b1 = fmaf((QB).y, (W).y, b1);        \
    b2 = fmaf((QB).z, (W).z, b2);        \
    b3 = fmaf((QB).w, (W).w, b3);        \
  } while (0)

// Branchless compare-swap of adjacent selection slots (strict <: stable).
#define BSTEP(dA, iA, dB, iB)              \
  do {                                     \
    bool s_ = (dB) < (dA);                 \
    float tlo = s_ ? (dB) : (dA);          \
    float thi = s_ ? (dA) : (dB);          \
    int   jlo = s_ ? (iB) : (iA);          \
    int   jhi = s_ ? (iA) : (iB);          \
    (dA) = tlo; (dB) = thi;                \
    (iA) = jlo; (iB) = jhi;                \
  } while (0)

#define BUBBLE20(D, I)                                                   \
  do {                                                                   \
    BSTEP(D##18, I##18, D##19, I##19); BSTEP(D##17, I##17, D##18, I##18);\
    BSTEP(D##16, I##16, D##17, I##17); BSTEP(D##15, I##15, D##16, I##16);\
    BSTEP(D##14, I##14, D##15, I##15); BSTEP(D##13, I##13, D##14, I##14);\
    BSTEP(D##12, I##12, D##13, I##13); BSTEP(D##11, I##11, D##12, I##12);\
    BSTEP(D##10, I##10, D##11, I##11); BSTEP(D##9,  I##9,  D##10, I##10);\
    BSTEP(D##8,  I##8,  D##9,  I##9);  BSTEP(D##7,  I##7,  D##8,  I##8); \
    BSTEP(D##6,  I##6,  D##7,  I##7);  BSTEP(D##5,  I##5,  D##6,  I##6); \
    BSTEP(D##4,  I##4,  D##5,  I##5);  BSTEP(D##3,  I##3,  D##4,  I##4); \
    BSTEP(D##2,  I##2,  D##3,  I##3);  BSTEP(D##1,  I##1,  D##2,  I##2); \
    BSTEP(D##0,  I##0,  D##1,  I##1);                                    \
  } while (0)

#define DECL20(D, I)                                                        \
  float D##0 = INF, D##1 = INF, D##2 = INF, D##3 = INF, D##4 = INF,         \
        D##5 = INF, D##6 = INF, D##7 = INF, D##8 = INF, D##9 = INF,         \
        D##10 = INF, D##11 = INF, D##12 = INF, D##13 = INF, D##14 = INF,    \
        D##15 = INF, D##16 = INF, D##17 = INF, D##18 = INF, D##19 = INF;    \
  int I##0 = 0, I##1 = 0, I##2 = 0, I##3 = 0, I##4 = 0,                     \
      I##5 = 0, I##6 = 0, I##7 = 0, I##8 = 0, I##9 = 0,                     \
      I##10 = 0, I##11 = 0, I##12 = 0, I##13 = 0, I##14 = 0,                \
      I##15 = 0, I##16 = 0, I##17 = 0, I##18 = 0, I##19 = 0;

#define STORE20(BASE, I)                                                    \
  do {                                                                      \
    pi[(BASE) + 0]  = I##0;  pi[(BASE) + 1]  = I##1;                        \
    pi[(BASE) + 2]  = I##2;  pi[(BASE) + 3]  = I##3;                        \
    pi[(BASE) + 4]  = I##4;  pi[(BASE) + 5]  = I##5;                        \
    pi[(BASE) + 6]  = I##6;  pi[(BASE) + 7]  = I##7;                        \
    pi[(BASE) + 8]  = I##8;  pi[(BASE) + 9]  = I##9;                        \
    pi[(BASE) + 10] = I##10; pi[(BASE) + 11] = I##11;                       \
    pi[(BASE) + 12] = I##12; pi[(BASE) + 13] = I##13;                       \
    pi[(BASE) + 14] = I##14; pi[(BASE) + 15] = I##15;                       \
    pi[(BASE) + 16] = I##16; pi[(BASE) + 17] = I##17;                       \
    pi[(BASE) + 18] = I##18; pi[(BASE) + 19] = I##19;                       \
  } while (0)

// Q=2 partial: each thread owns rows (base+tid) and (base+tid+256).
template <int P>
__global__ __launch_bounds__(256)
__attribute__((amdgpu_waves_per_eu(2, 2)))
void knn_partial2_kernel(
    const float* __restrict__ x, const float* __restrict__ x2,
    int* __restrict__ pi) {
  __shared__ float tile[TILE * DD];   // 16 KB candidate tile
  __shared__ float x2t[TILE];

  const int tid   = threadIdx.x;
  const int rb    = blockIdx.x / P;   // 512-row block id
  const int chunk = blockIdx.x % P;
  const int base_row = rb * 512;
  const int b     = base_row >> 13;   // batch (8192 % 512 == 0)
  const int rowA  = base_row + tid;
  const int rowB  = rowA + 256;
  const int jA    = rowA & (MM - 1);
  const int jB    = jA + 256;

  const float* __restrict__ xb  = x + (size_t)b * MM * DD;
  const float* __restrict__ x2b = x2 + b * MM;

  const float4* qpA = (const float4*)(xb + (size_t)jA * DD);
  const float4* qpB = (const float4*)(xb + (size_t)jB * DD);
  float4 qa0 = qpA[0],  qa1 = qpA[1],  qa2 = qpA[2],  qa3 = qpA[3];
  float4 qa4 = qpA[4],  qa5 = qpA[5],  qa6 = qpA[6],  qa7 = qpA[7];
  float4 qa8 = qpA[8],  qa9 = qpA[9],  qa10 = qpA[10], qa11 = qpA[11];
  float4 qa12 = qpA[12], qa13 = qpA[13], qa14 = qpA[14], qa15 = qpA[15];
  float4 qb0 = qpB[0],  qb1 = qpB[1],  qb2 = qpB[2],  qb3 = qpB[3];
  float4 qb4 = qpB[4],  qb5 = qpB[5],  qb6 = qpB[6],  qb7 = qpB[7];
  float4 qb8 = qpB[8],  qb9 = qpB[9],  qb10 = qpB[10], qb11 = qpB[11];
  float4 qb12 = qpB[12], qb13 = qpB[13], qb14 = qpB[14], qb15 = qpB[15];

  const float INF = __builtin_inff();
  DECL20(da, ia)
  DECL20(db, ib)

  const int C  = MM / P;
  const int c0 = chunk * C;

  for (int ts = c0; ts < c0 + C; ts += TILE) {
    __syncthreads();
    {
      const float4* gsrc = (const float4*)(xb + (size_t)ts * DD);
      float4* lds4 = (float4*)tile;
#pragma unroll
      for (int u = 0; u < 4; ++u) lds4[tid + 256 * u] = gsrc[tid + 256 * u];
      if (tid < TILE / 4)
        ((float4*)x2t)[tid] = ((const float4*)(x2b + ts))[tid];
    }
    __syncthreads();

#pragma unroll 2
    for (int t = 0; t < TILE; ++t) {
      const float4* cp = (const float4*)(tile + t * DD);
      float a0 = 0.f, a1 = 0.f, a2 = 0.f, a3 = 0.f;
      float b0 = 0.f, b1 = 0.f, b2 = 0.f, b3 = 0.f;
      {
        float4 w;
        w = cp[0];  DOT4W(qa0,  qb0,  w);
        w = cp[1];  DOT4W(qa1,  qb1,  w);
        w = cp[2];  DOT4W(qa2,  qb2,  w);
        w = cp[3];  DOT4W(qa3,  qb3,  w);
        w = cp[4];  DOT4W(qa4,  qb4,  w);
        w = cp[5];  DOT4W(qa5,  qb5,  w);
        w = cp[6];  DOT4W(qa6,  qb6,  w);
        w = cp[7];  DOT4W(qa7,  qb7,  w);
        w = cp[8];  DOT4W(qa8,  qb8,  w);
        w = cp[9];  DOT4W(qa9,  qb9,  w);
        w = cp[10]; DOT4W(qa10, qb10, w);
        w = cp[11]; DOT4W(qa11, qb11, w);
        w = cp[12]; DOT4W(qa12, qb12, w);
        w = cp[13]; DOT4W(qa13, qb13, w);
        w = cp[14]; DOT4W(qa14, qb14, w);
        w = cp[15]; DOT4W(qa15, qb15, w);
      }
      float x2c = x2t[t];
      float dotA = (a0 + a1) + (a2 + a3);
      float dotB = (b0 + b1) + (b2 + b3);
      float keyA = fmaf(-2.f, dotA, x2c);
      float keyB = fmaf(-2.f, dotB, x2c);

      bool insA = keyA < da19;
      da19 = insA ? keyA : da19;
      ia19 = insA ? (ts + t) : ia19;
      BUBBLE20(da, ia);

      bool insB = keyB < db19;
      db19 = insB ? keyB : db19;
      ib19 = insB ? (ts + t) : ib19;
      BUBBLE20(db, ib);
    }
  }

  size_t baseA = ((size_t)rowA * P + chunk) * TK;
  size_t baseB = ((size_t)rowB * P + chunk) * TK;
  STORE20(baseA, ia);
  STORE20(baseB, ib);
}

// Q=1 partial (R12 path, used as workspace fallback).
template <int P>
__global__ __launch_bounds__(256)
__attribute__((amdgpu_waves_per_eu(2, 2)))
void knn_partial_kernel(
    const float* __restrict__ x, const float* __restrict__ x2,
    int* __restrict__ pi) {
  __shared__ float tile[TILE * DD];
  __shared__ float x2t[TILE];

  const int tid   = threadIdx.x;
  const int rb    = blockIdx.x / P;
  const int chunk = blockIdx.x % P;
  const int b     = rb >> 5;
  const int row   = rb * 256 + tid;
  const int j     = row - b * MM;

  const float* __restrict__ xb  = x + (size_t)b * MM * DD;
  const float* __restrict__ x2b = x2 + b * MM;

  const float4* qp = (const float4*)(xb + (size_t)j * DD);
  float4 q0 = qp[0],  q1 = qp[1],  q2 = qp[2],  q3 = qp[3];
  float4 q4 = qp[4],  q5 = qp[5],  q6 = qp[6],  q7 = qp[7];
  float4 q8 = qp[8],  q9 = qp[9],  q10 = qp[10], q11 = qp[11];
  float4 q12 = qp[12], q13 = qp[13], q14 = qp[14], q15 = qp[15];

  const float INF = __builtin_inff();
  DECL20(d, i)

  const int C  = MM / P;
  const int c0 = chunk * C;

  for (int ts = c0; ts < c0 + C; ts += TILE) {
    __syncthreads();
    {
      const float4* gsrc = (const float4*)(xb + (size_t)ts * DD);
      float4* lds4 = (float4*)tile;
#pragma unroll
      for (int u = 0; u < 4; ++u) lds4[tid + 256 * u] = gsrc[tid + 256 * u];
      if (tid < TILE / 4)
        ((float4*)x2t)[tid] = ((const float4*)(x2b + ts))[tid];
    }
    __syncthreads();

#pragma unroll 2
    for (int t = 0; t < TILE; ++t) {
      const float4* cp = (const float4*)(tile + t * DD);
      float a0 = 0.f, a1 = 0.f, a2 = 0.f, a3 = 0.f;
      {
        float4 w;
        w = cp[0];  a0 = fmaf(q0.x, w.x, a0);  a1 = fmaf(q0.y, w.y, a1);
                    a2 = fmaf(q0.z, w.z, a2);  a3 = fmaf(q0.w, w.w, a3);
        w = cp[1];  a0 = fmaf(q1.x, w.x, a0);  a1 = fmaf(q1.y, w.y, a1);
                    a2 = fmaf(q1.z, w.z, a2);  a3 = fmaf(q1.w, w.w, a3);
        w = cp[2];  a0 = fmaf(q2.x, w.x, a0);  a1 = fmaf(q2.y, w.y, a1);
                    a2 = fmaf(q2.z, w.z, a2);  a3 = fmaf(q2.w, w.w, a3);
        w = cp[3];  a0 = fmaf(q3.x, w.x, a0);  a1 = fmaf(q3.y, w.y, a1);
                    a2 = fmaf(q3.z, w.z, a2);  a3 = fmaf(q3.w, w.w, a3);
        w = cp[4];  a0 = fmaf(q4.x, w.x, a0);  a1 = fmaf(q4.y, w.y, a1);
                    a2 = fmaf(q4.z, w.z, a2);  a3 = fmaf(q4.w, w.w, a3);
        w = cp[5];  a0 = fmaf(q5.x, w.x, a0);  a1 = fmaf(q5.y, w.y, a1);
                    a2 = fmaf(q5.z, w.z, a2);  a3 = fmaf(q5.w, w.w, a3);
        w = cp[6];  a0 = fmaf(q6.x, w.x, a0);  a1 = fmaf(q6.y, w.y, a1);
                    a2 = fmaf(q6.z, w.z, a2);  a3 = fmaf(q6.w, w.w, a3);
        w = cp[7];  a0 = fmaf(q7.x, w.x, a0);  a1 = fmaf(q7.y, w.y, a1);
                    a2 = fmaf(q7.z, w.z, a2);  a3 = fmaf(q7.w, w.w, a3);
        w = cp[8];  a0 = fmaf(q8.x, w.x, a0);  a1 = fmaf(q8.y, w.y, a1);
                    a2 = fmaf(q8.z, w.z, a2);  a3 = fmaf(q8.w, w.w, a3);
        w = cp[9];  a0 = fmaf(q9.x, w.x, a0);  a1 = fmaf(q9.y, w.y, a1);
                    a2 = fmaf(q9.z, w.z, a2);  a3 = fmaf(q9.w, w.w, a3);
        w = cp[10]; a0 = fmaf(q10.x, w.x, a0); a1 = fmaf(q10.y, w.y, a1);
                    a2 = fmaf(q10.z, w.z, a2); a3 = fmaf(q10.w, w.w, a3);
        w = cp[11]; a0 = fmaf(q11.x, w.x, a0); a1 = fmaf(q11.y, w.y, a1);
                    a2 = fmaf(q11.z, w.z, a2); a3 = fmaf(q11.w, w.w, a3);
        w = cp[12]; a0 = fmaf(q12.x, w.x, a0); a1 = fmaf(q12.y, w.y, a1);
                    a2 = fmaf(q12.z, w.z, a2); a3 = fmaf(q12.w, w.w, a3);
        w = cp[13]; a0 = fmaf(q13.x, w.x, a0); a1 = fmaf(q13.y, w.y, a1);
                    a2 = fmaf(q13.z, w.z, a2); a3 = fmaf(q13.w, w.w, a3);
        w = cp[14]; a0 = fmaf(q14.x, w.x, a0); a1 = fmaf(q14.y, w.y, a1);
                    a2 = fmaf(q14.z, w.z, a2); a3 = fmaf(q14.w, w.w, a3);
        w = cp[15]; a0 = fmaf(q15.x, w.x, a0); a1 = fmaf(q15.y, w.y, a1);
                    a2 = fmaf(q15.z, w.z, a2); a3 = fmaf(q15.w, w.w, a3);
      }
      float dot = (a0 + a1) + (a2 + a3);
      float key = fmaf(-2.f, dot, x2t[t]);

      bool ins = key < d19;
      d19 = ins ? key : d19;
      i19 = ins ? (ts + t) : i19;
      BUBBLE20(d, i);
    }
  }

  size_t base = ((size_t)row * P + chunk) * TK;
  STORE20(base, i);
}

// FROZEN-numerics einsum block: per-product rounding then reversed adds.
#define EBLK(QA, QB, QC, QD, W0, W1, W2, W3)                                  \
  do {                                                                        \
    v0 = (QA).x * (W0).x +                                                    \
         ((QB).x * (W1).x + ((QC).x * (W2).x + ((QD).x * (W3).x + v0)));      \
    v1 = (QA).y * (W0).y +                                                    \
         ((QB).y * (W1).y + ((QC).y * (W2).y + ((QD).y * (W3).y + v1)));      \
    v2 = (QA).z * (W0).z +                                                    \
         ((QB).z * (W1).z + ((QC).z * (W2).z + ((QD).z * (W3).z + v2)));      \
    v3 = (QA).w * (W0).w +                                                    \
         ((QB).w * (W1).w + ((QC).w * (W2).w + ((QD).w * (W3).w + v3)));      \
  } while (0)

template <int P>
__global__ __launch_bounds__(256)
__attribute__((amdgpu_waves_per_eu(2, 2)))
void knn_rescore_kernel(
    const float* __restrict__ x, const float* __restrict__ x2,
    const int* __restrict__ pi,
    int* __restrict__ src, int* __restrict__ dst) {
#pragma clang fp contract(off)
  int r = blockIdx.x * 256 + threadIdx.x;
  if (r >= NROWS) return;
  const int b = r >> 13;
  const int j = r & (MM - 1);
  const float* __restrict__ xb = x + (size_t)b * MM * DD;
  const float x2j = x2[r];

  const float4* qp = (const float4*)(xb + (size_t)j * DD);
  float4 q0 = qp[0],  q1 = qp[1],  q2 = qp[2],  q3 = qp[3];
  float4 q4 = qp[4],  q5 = qp[5],  q6 = qp[6],  q7 = qp[7];
  float4 q8 = qp[8],  q9 = qp[9],  q10 = qp[10], q11 = qp[11];
  float4 q12 = qp[12], q13 = qp[13], q14 = qp[14], q15 = qp[15];

  float bd[KK];
  int   bi[KK];
#pragma unroll
  for (int t = 0; t < KK; ++t) {
    bd[t] = __builtin_inff();
    bi[t] = 0x7fffffff;
  }

  const int CAND = P * TK;
  size_t base = (size_t)r * CAND;

  for (int t = 0; t < CAND; ++t) {
    int c = pi[base + t];
    const float4* pp = (const float4*)(xb + (size_t)c * DD);
    // FROZEN numerics: einsum baseline-SSE reversed muladd chain.
    float v0 = 0.f, v1 = 0.f, v2 = 0.f, v3 = 0.f;
    {
      float4 w0 = pp[0], w1 = pp[1], w2 = pp[2], w3 = pp[3];
      EBLK(q0, q1, q2, q3, w0, w1, w2, w3);
    }
    {
      float4 w0 = pp[4], w1 = pp[5], w2 = pp[6], w3 = pp[7];
      EBLK(q4, q5, q6, q7, w0, w1, w2, w3);
    }
    {
      float4 w0 = pp[8], w1 = pp[9], w2 = pp[10], w3 = pp[11];
      EBLK(q8, q9, q10, q11, w0, w1, w2, w3);
    }
    {
      float4 w0 = pp[12], w1 = pp[13], w2 = pp[14], w3 = pp[15];
      EBLK(q12, q13, q14, q15, w0, w1, w2, w3);
    }
    float dotf = (v0 + v1) + (v2 + v3);
    float s  = x2j + x2[b * MM + c];
    float tm = 2.0f * dotf;
    float d2 = s - tm;

    bool lt = (d2 < bd[KK - 1]) ||
              (d2 == bd[KK - 1] && c < bi[KK - 1]);
    if (lt) {
      bd[KK - 1] = d2;
      bi[KK - 1] = c;
#pragma unroll
      for (int t2 = KK - 1; t2 > 0; --t2) {
        bool sw = (bd[t2] < bd[t2 - 1]) ||
                  (bd[t2] == bd[t2 - 1] && bi[t2] < bi[t2 - 1]);
        float dlo = sw ? bd[t2] : bd[t2 - 1];
        float dhi = sw ? bd[t2 - 1] : bd[t2];
        int   ilo = sw ? bi[t2] : bi[t2 - 1];
        int   ihi = sw ? bi[t2 - 1] : bi[t2];
        bd[t2 - 1] = dlo; bd[t2] = dhi;
        bi[t2 - 1] = ilo; bi[t2] = ihi;
      }
    }
  }

#pragma unroll
  for (int t = 0; t < KK; ++t) {
    src[(size_t)r * KK + t] = b * MM + bi[t];
    dst[(size_t)r * KK + t] = r;
  }
}

template <int P, bool Q2>
static void launch_all(const float* x, int* out, void* d_ws, hipStream_t stream) {
  char* ws = (char*)d_ws;
  float* x2 = (float*)ws;
  int*   pi = (int*)(ws + (size_t)NROWS * sizeof(float));

  int* src = out;
  int* dst = out + (size_t)NROWS * KK;

  norms_np_kernel<<<NROWS / 256, 256, 0, stream>>>(x, x2);
  if (Q2) {
    knn_partial2_kernel<P><<<(NROWS / 512) * P, 256, 0, stream>>>(x, x2, pi);
  } else {
    knn_partial_kernel<P><<<(NROWS / 256) * P, 256, 0, stream>>>(x, x2, pi);
  }
  knn_rescore_kernel<P><<<NROWS / 256, 256, 0, stream>>>(x, x2, pi, src, dst);
}

extern "C" void kernel_launch(void* const* d_in, const int* in_sizes, int n_in,
                              void* d_out, int out_size, void* d_ws, size_t ws_size,
                              hipStream_t stream) {
  const float* x = (const float*)d_in[0];
  int* out = (int*)d_out;

  auto need = [](int P) {
    return (size_t)NROWS * sizeof(float) +
           (size_t)NROWS * P * TK * sizeof(int);
  };

  if (ws_size >= need(8)) {
    launch_all<8, true>(x, out, d_ws, stream);   // Q=2, 2048 waves
  } else if (ws_size >= need(4)) {
    launch_all<4, false>(x, out, d_ws, stream);  // R12 proven path
  } else if (ws_size >= need(2)) {
    launch_all<2, false>(x, out, d_ws, stream);
  } else {
    launch_all<1, false>(x, out, d_ws, stream);
  }
}

// Round 14
// 1327.524 us; speedup vs baseline: 4.1424x; 4.1424x over previous
//
#include <hip/hip_runtime.h>

// KNNGraph bruteforce-blas, euclidean, k=16, include self.
// x: (N=4, M=8192, D=64) fp32. Output: int32 src[N*M*K] then dst[N*M*K].
//
// VALIDATED reference model (R9, absmax=0 — numerics FROZEN):
//   x2  = np.sum(x*x,-1): squares rounded per-element, FLOAT_pairwise_sum
//         n=64 NPY_SIMD path: 4 vec accs (vstep=4), serial blocks,
//         combine (r0+r1)+(r2+r3), double-hadd (S0+S1)+(S2+S3).
//   dot = np.einsum baseline-SSE: per-16 block REVERSED muladd chain
//         v_l = p0l+(p1l+(p2l+(p3l+v_l))), double-hadd (v0+v1)+(v2+v3).
//   d2  = fl(fl(x2j+x2c) - fl(2*dot)); stable ties by lower index.
//
// R14: packed-u32 selection. R13's Q=2 spilled (10.9 GB scratch FETCH) —
// selection regs were the budget killer. Stage-A key is heuristic, so pack
// monotone-mapped key (top 21 bits) + chunk-relative idx (low bits) into ONE
// u32; sorted insert = v_min_u32/v_max_u32 pairs. Selection: 40->20 regs,
// ~104->~45 VALU per candidate. Q=1, P=4 (R12-proven shape).

#define MM 8192
#define NN 4
#define DD 64
#define KK 16
#define TK 20            // stage-A keep per chunk (16 + 4 safety margin)
#define TILE 64          // candidate tile rows staged in LDS
#define NROWS (NN * MM)  // 32768

// numpy SIMD pairwise sum of squares (SSE baseline), n=64. FROZEN.
__global__ __launch_bounds__(256) void norms_np_kernel(
    const float* __restrict__ x, float* __restrict__ x2) {
#pragma clang fp contract(off)
  int r = blockIdx.x * 256 + threadIdx.x;
  if (r >= NROWS) return;
  const float4* p = (const float4*)(x + (size_t)r * DD);
  float s[DD];
#pragma unroll
  for (int i = 0; i < DD / 4; ++i) {
    float4 v = p[i];
    s[4 * i + 0] = v.x * v.x;
    s[4 * i + 1] = v.y * v.y;
    s[4 * i + 2] = v.z * v.z;
    s[4 * i + 3] = v.w * v.w;
  }
  float acc[4][4];
#pragma unroll
  for (int c = 0; c < 4; ++c)
#pragma unroll
    for (int l = 0; l < 4; ++l) acc[c][l] = s[4 * c + l];
#pragma unroll
  for (int b = 1; b < 4; ++b)
#pragma unroll
    for (int c = 0; c < 4; ++c)
#pragma unroll
      for (int l = 0; l < 4; ++l)
        acc[c][l] = acc[c][l] + s[16 * b + 4 * c + l];
  float S[4];
#pragma unroll
  for (int l = 0; l < 4; ++l)
    S[l] = (acc[0][l] + acc[1][l]) + (acc[2][l] + acc[3][l]);
  x2[r] = (S[0] + S[1]) + (S[2] + S[3]);
}

// Packed compare-swap: sA=min, sB=max (u32 => (quantized key, idx) lex).
#define PSTEP(sA, sB)                       \
  do {                                      \
    unsigned lo_ = min((sA), (sB));         \
    unsigned hi_ = max((sA), (sB));         \
    (sA) = lo_; (sB) = hi_;                 \
  } while (0)

#define PBUBBLE20(S)                                              \
  do {                                                            \
    PSTEP(S##18, S##19); PSTEP(S##17, S##18); PSTEP(S##16, S##17);\
    PSTEP(S##15, S##16); PSTEP(S##14, S##15); PSTEP(S##13, S##14);\
    PSTEP(S##12, S##13); PSTEP(S##11, S##12); PSTEP(S##10, S##11);\
    PSTEP(S##9,  S##10); PSTEP(S##8,  S##9);  PSTEP(S##7,  S##8); \
    PSTEP(S##6,  S##7);  PSTEP(S##5,  S##6);  PSTEP(S##4,  S##5); \
    PSTEP(S##3,  S##4);  PSTEP(S##2,  S##3);  PSTEP(S##1,  S##2); \
    PSTEP(S##0,  S##1);                                           \
  } while (0)

template <int P>
__global__ __launch_bounds__(256)
__attribute__((amdgpu_waves_per_eu(2, 2)))
void knn_partial_kernel(
    const float* __restrict__ x, const float* __restrict__ x2,
    int* __restrict__ pi) {
  // idx bits: chunk-relative candidate index.
  constexpr int IB = (P == 8) ? 10 : (P == 4) ? 11 : (P == 2) ? 12 : 13;
  constexpr unsigned IMASK = (1u << IB) - 1u;
  constexpr unsigned QMASK = ~IMASK;

  __shared__ float tile[TILE * DD];   // 16 KB candidate tile
  __shared__ float x2t[TILE];

  const int tid   = threadIdx.x;
  const int rb    = blockIdx.x / P;
  const int chunk = blockIdx.x % P;
  const int b     = rb >> 5;
  const int row   = rb * 256 + tid;
  const int j     = row - b * MM;

  const float* __restrict__ xb  = x + (size_t)b * MM * DD;
  const float* __restrict__ x2b = x2 + b * MM;

  const float4* qp = (const float4*)(xb + (size_t)j * DD);
  float4 q0 = qp[0],  q1 = qp[1],  q2 = qp[2],  q3 = qp[3];
  float4 q4 = qp[4],  q5 = qp[5],  q6 = qp[6],  q7 = qp[7];
  float4 q8 = qp[8],  q9 = qp[9],  q10 = qp[10], q11 = qp[11];
  float4 q12 = qp[12], q13 = qp[13], q14 = qp[14], q15 = qp[15];

  // Selection: 20 packed u32 slots, ascending (s0 best).
  unsigned s0 = 0xFFFFFFFFu, s1 = 0xFFFFFFFFu, s2 = 0xFFFFFFFFu,
           s3 = 0xFFFFFFFFu, s4 = 0xFFFFFFFFu, s5 = 0xFFFFFFFFu,
           s6 = 0xFFFFFFFFu, s7 = 0xFFFFFFFFu, s8 = 0xFFFFFFFFu,
           s9 = 0xFFFFFFFFu, s10 = 0xFFFFFFFFu, s11 = 0xFFFFFFFFu,
           s12 = 0xFFFFFFFFu, s13 = 0xFFFFFFFFu, s14 = 0xFFFFFFFFu,
           s15 = 0xFFFFFFFFu, s16 = 0xFFFFFFFFu, s17 = 0xFFFFFFFFu,
           s18 = 0xFFFFFFFFu, s19 = 0xFFFFFFFFu;

  const int C  = MM / P;
  const int c0 = chunk * C;

  for (int ts = c0; ts < c0 + C; ts += TILE) {
    __syncthreads();
    {
      const float4* gsrc = (const float4*)(xb + (size_t)ts * DD);
      float4* lds4 = (float4*)tile;
#pragma unroll
      for (int u = 0; u < 4; ++u) lds4[tid + 256 * u] = gsrc[tid + 256 * u];
      if (tid < TILE / 4)
        ((float4*)x2t)[tid] = ((const float4*)(x2b + ts))[tid];
    }
    __syncthreads();

#pragma unroll 2
    for (int t = 0; t < TILE; ++t) {
      const float4* cp = (const float4*)(tile + t * DD);
      float a0 = 0.f, a1 = 0.f, a2 = 0.f, a3 = 0.f;
      {
        float4 w;
        w = cp[0];  a0 = fmaf(q0.x, w.x, a0);  a1 = fmaf(q0.y, w.y, a1);
                    a2 = fmaf(q0.z, w.z, a2);  a3 = fmaf(q0.w, w.w, a3);
        w = cp[1];  a0 = fmaf(q1.x, w.x, a0);  a1 = fmaf(q1.y, w.y, a1);
                    a2 = fmaf(q1.z, w.z, a2);  a3 = fmaf(q1.w, w.w, a3);
        w = cp[2];  a0 = fmaf(q2.x, w.x, a0);  a1 = fmaf(q2.y, w.y, a1);
                    a2 = fmaf(q2.z, w.z, a2);  a3 = fmaf(q2.w, w.w, a3);
        w = cp[3];  a0 = fmaf(q3.x, w.x, a0);  a1 = fmaf(q3.y, w.y, a1);
                    a2 = fmaf(q3.z, w.z, a2);  a3 = fmaf(q3.w, w.w, a3);
        w = cp[4];  a0 = fmaf(q4.x, w.x, a0);  a1 = fmaf(q4.y, w.y, a1);
                    a2 = fmaf(q4.z, w.z, a2);  a3 = fmaf(q4.w, w.w, a3);
        w = cp[5];  a0 = fmaf(q5.x, w.x, a0);  a1 = fmaf(q5.y, w.y, a1);
                    a2 = fmaf(q5.z, w.z, a2);  a3 = fmaf(q5.w, w.w, a3);
        w = cp[6];  a0 = fmaf(q6.x, w.x, a0);  a1 = fmaf(q6.y, w.y, a1);
                    a2 = fmaf(q6.z, w.z, a2);  a3 = fmaf(q6.w, w.w, a3);
        w = cp[7];  a0 = fmaf(q7.x, w.x, a0);  a1 = fmaf(q7.y, w.y, a1);
                    a2 = fmaf(q7.z, w.z, a2);  a3 = fmaf(q7.w, w.w, a3);
        w = cp[8];  a0 = fmaf(q8.x, w.x, a0);  a1 = fmaf(q8.y, w.y, a1);
                    a2 = fmaf(q8.z, w.z, a2);  a3 = fmaf(q8.w, w.w, a3);
        w = cp[9];  a0 = fmaf(q9.x, w.x, a0);  a1 = fmaf(q9.y, w.y, a1);
                    a2 = fmaf(q9.z, w.z, a2);  a3 = fmaf(q9.w, w.w, a3);
        w = cp[10]; a0 = fmaf(q10.x, w.x, a0); a1 = fmaf(q10.y, w.y, a1);
                    a2 = fmaf(q10.z, w.z, a2); a3 = fmaf(q10.w, w.w, a3);
        w = cp[11]; a0 = fmaf(q11.x, w.x, a0); a1 = fmaf(q11.y, w.y, a1);
                    a2 = fmaf(q11.z, w.z, a2); a3 = fmaf(q11.w, w.w, a3);
        w = cp[12]; a0 = fmaf(q12.x, w.x, a0); a1 = fmaf(q12.y, w.y, a1);
                    a2 = fmaf(q12.z, w.z, a2); a3 = fmaf(q12.w, w.w, a3);
        w = cp[13]; a0 = fmaf(q13.x, w.x, a0); a1 = fmaf(q13.y, w.y, a1);
                    a2 = fmaf(q13.z, w.z, a2); a3 = fmaf(q13.w, w.w, a3);
        w = cp[14]; a0 = fmaf(q14.x, w.x, a0); a1 = fmaf(q14.y, w.y, a1);
                    a2 = fmaf(q14.z, w.z, a2); a3 = fmaf(q14.w, w.w, a3);
        w = cp[15]; a0 = fmaf(q15.x, w.x, a0); a1 = fmaf(q15.y, w.y, a1);
                    a2 = fmaf(q15.z, w.z, a2); a3 = fmaf(q15.w, w.w, a3);
      }
      float dot = (a0 + a1) + (a2 + a3);
      float key = fmaf(-2.f, dot, x2t[t]);

      // Monotone float->u32, quantize, pack chunk-relative idx.
      int ki = __float_as_int(key);
      unsigned mono = (unsigned)ki ^ ((unsigned)(ki >> 31) | 0x80000000u);
      unsigned pk = (mono & QMASK) | (unsigned)(ts - c0 + t);

      s19 = min(s19, pk);   // replace worst iff better
      PBUBBLE20(s);         // re-sort (2 VALU per step)
    }
  }

  size_t base = ((size_t)row * P + chunk) * TK;
  pi[base + 0]  = (int)(s0  & IMASK) + c0;
  pi[base + 1]  = (int)(s1  & IMASK) + c0;
  pi[base + 2]  = (int)(s2  & IMASK) + c0;
  pi[base + 3]  = (int)(s3  & IMASK) + c0;
  pi[base + 4]  = (int)(s4  & IMASK) + c0;
  pi[base + 5]  = (int)(s5  & IMASK) + c0;
  pi[base + 6]  = (int)(s6  & IMASK) + c0;
  pi[base + 7]  = (int)(s7  & IMASK) + c0;
  pi[base + 8]  = (int)(s8  & IMASK) + c0;
  pi[base + 9]  = (int)(s9  & IMASK) + c0;
  pi[base + 10] = (int)(s10 & IMASK) + c0;
  pi[base + 11] = (int)(s11 & IMASK) + c0;
  pi[base + 12] = (int)(s12 & IMASK) + c0;
  pi[base + 13] = (int)(s13 & IMASK) + c0;
  pi[base + 14] = (int)(s14 & IMASK) + c0;
  pi[base + 15] = (int)(s15 & IMASK) + c0;
  pi[base + 16] = (int)(s16 & IMASK) + c0;
  pi[base + 17] = (int)(s17 & IMASK) + c0;
  pi[base + 18] = (int)(s18 & IMASK) + c0;
  pi[base + 19] = (int)(s19 & IMASK) + c0;
}

// FROZEN-numerics einsum block: per-product rounding then reversed adds.
#define EBLK(QA, QB, QC, QD, W0, W1, W2, W3)                                  \
  do {                                                                        \
    v0 = (QA).x * (W0).x +                                                    \
         ((QB).x * (W1).x + ((QC).x * (W2).x + ((QD).x * (W3).x + v0)));      \
    v1 = (QA).y * (W0).y +                                                    \
         ((QB).y * (W1).y + ((QC).y * (W2).y + ((QD).y * (W3).y + v1)));      \
    v2 = (QA).z * (W0).z +                                                    \
         ((QB).z * (W1).z + ((QC).z * (W2).z + ((QD).z * (W3).z + v2)));      \
    v3 = (QA).w * (W0).w +                                                    \
         ((QB).w * (W1).w + ((QC).w * (W2).w + ((QD).w * (W3).w + v3)));      \
  } while (0)

template <int P>
__global__ __launch_bounds__(256)
__attribute__((amdgpu_waves_per_eu(2, 2)))
void knn_rescore_kernel(
    const float* __restrict__ x, const float* __restrict__ x2,
    const int* __restrict__ pi,
    int* __restrict__ src, int* __restrict__ dst) {
#pragma clang fp contract(off)
  int r = blockIdx.x * 256 + threadIdx.x;
  if (r >= NROWS) return;
  const int b = r >> 13;
  const int j = r & (MM - 1);
  const float* __restrict__ xb = x + (size_t)b * MM * DD;
  const float x2j = x2[r];

  const float4* qp = (const float4*)(xb + (size_t)j * DD);
  float4 q0 = qp[0],  q1 = qp[1],  q2 = qp[2],  q3 = qp[3];
  float4 q4 = qp[4],  q5 = qp[5],  q6 = qp[6],  q7 = qp[7];
  float4 q8 = qp[8],  q9 = qp[9],  q10 = qp[10], q11 = qp[11];
  float4 q12 = qp[12], q13 = qp[13], q14 = qp[14], q15 = qp[15];

  float bd[KK];
  int   bi[KK];
#pragma unroll
  for (int t = 0; t < KK; ++t) {
    bd[t] = __builtin_inff();
    bi[t] = 0x7fffffff;
  }

  const int CAND = P * TK;
  size_t base = (size_t)r * CAND;

  for (int t = 0; t < CAND; ++t) {
    int c = pi[base + t];
    const float4* pp = (const float4*)(xb + (size_t)c * DD);
    // FROZEN numerics: einsum baseline-SSE reversed muladd chain.
    float v0 = 0.f, v1 = 0.f, v2 = 0.f, v3 = 0.f;
    {
      float4 w0 = pp[0], w1 = pp[1], w2 = pp[2], w3 = pp[3];
      EBLK(q0, q1, q2, q3, w0, w1, w2, w3);
    }
    {
      float4 w0 = pp[4], w1 = pp[5], w2 = pp[6], w3 = pp[7];
      EBLK(q4, q5, q6, q7, w0, w1, w2, w3);
    }
    {
      float4 w0 = pp[8], w1 = pp[9], w2 = pp[10], w3 = pp[11];
      EBLK(q8, q9, q10, q11, w0, w1, w2, w3);
    }
    {
      float4 w0 = pp[12], w1 = pp[13], w2 = pp[14], w3 = pp[15];
      EBLK(q12, q13, q14, q15, w0, w1, w2, w3);
    }
    float dotf = (v0 + v1) + (v2 + v3);
    float s  = x2j + x2[b * MM + c];
    float tm = 2.0f * dotf;
    float d2 = s - tm;

    bool lt = (d2 < bd[KK - 1]) ||
              (d2 == bd[KK - 1] && c < bi[KK - 1]);
    if (lt) {
      bd[KK - 1] = d2;
      bi[KK - 1] = c;
#pragma unroll
      for (int t2 = KK - 1; t2 > 0; --t2) {
        bool sw = (bd[t2] < bd[t2 - 1]) ||
                  (bd[t2] == bd[t2 - 1] && bi[t2] < bi[t2 - 1]);
        float dlo = sw ? bd[t2] : bd[t2 - 1];
        float dhi = sw ? bd[t2 - 1] : bd[t2];
        int   ilo = sw ? bi[t2] : bi[t2 - 1];
        int   ihi = sw ? bi[t2 - 1] : bi[t2];
        bd[t2 - 1] = dlo; bd[t2] = dhi;
        bi[t2 - 1] = ilo; bi[t2] = ihi;
      }
    }
  }

#pragma unroll
  for (int t = 0; t < KK; ++t) {
    src[(size_t)r * KK + t] = b * MM + bi[t];
    dst[(size_t)r * KK + t] = r;
  }
}

template <int P>
static void launch_all(const float* x, int* out, void* d_ws, hipStream_t stream) {
  char* ws = (char*)d_ws;
  float* x2 = (float*)ws;
  int*   pi = (int*)(ws + (size_t)NROWS * sizeof(float));

  int* src = out;
  int* dst = out + (size_t)NROWS * KK;

  norms_np_kernel<<<NROWS / 256, 256, 0, stream>>>(x, x2);
  knn_partial_kernel<P><<<(NROWS / 256) * P, 256, 0, stream>>>(x, x2, pi);
  knn_rescore_kernel<P><<<NROWS / 256, 256, 0, stream>>>(x, x2, pi, src, dst);
}

extern "C" void kernel_launch(void* const* d_in, const int* in_sizes, int n_in,
                              void* d_out, int out_size, void* d_ws, size_t ws_size,
                              hipStream_t stream) {
  const float* x = (const float*)d_in[0];
  int* out = (int*)d_out;

  auto need = [](int P) {
    return (size_t)NROWS * sizeof(float) +
           (size_t)NROWS * P * TK * sizeof(int);
  };

  if (ws_size >= need(4)) {
    launch_all<4>(x, out, d_ws, stream);
  } else if (ws_size >= need(2)) {
    launch_all<2>(x, out, d_ws, stream);
  } else {
    launch_all<1>(x, out, d_ws, stream);
  }
}

// Round 15
// 1247.888 us; speedup vs baseline: 4.4067x; 1.0638x over previous
//
#include <hip/hip_runtime.h>

// KNNGraph bruteforce-blas, euclidean, k=16, include self.
// x: (N=4, M=8192, D=64) fp32. Output: int32 src[N*M*K] then dst[N*M*K].
//
// VALIDATED reference model (R9, absmax=0 — numerics FROZEN):
//   x2  = np.sum(x*x,-1): squares rounded per-element, FLOAT_pairwise_sum
//         n=64 NPY_SIMD path: 4 vec accs (vstep=4), serial blocks,
//         combine (r0+r1)+(r2+r3), double-hadd (S0+S1)+(S2+S3).
//   dot = np.einsum baseline-SSE: per-16 block REVERSED muladd chain
//         v_l = p0l+(p1l+(p2l+(p3l+v_l))), double-hadd (v0+v1)+(v2+v3).
//   d2  = fl(fl(x2j+x2c) - fl(2*dot)); stable ties by lower index.
//
// R15: LDS was the binding pipe (16 ds_read_b128/visit -> ~875 us demand).
//  (1) Q=2 query blocking: each candidate float4 read once, feeds 2 rows
//      -> LDS demand halves. Fits now: 128 q + 40 packed-sel < 256 VGPR
//      (R13's Q=2 spill was the 80-reg float/int selection).
//  (2) v_pk_fma_f32 dot via float2 + __builtin_elementwise_fma (exact fp32).
//  (3) P=8 keeps 2048 waves. Selection stays R14's packed-u32 bubble.

#define MM 8192
#define NN 4
#define DD 64
#define KK 16
#define TK 20            // stage-A keep per chunk (16 + 4 safety margin)
#define TILE 64          // candidate tile rows staged in LDS
#define NROWS (NN * MM)  // 32768

typedef float f32x2 __attribute__((ext_vector_type(2)));

// numpy SIMD pairwise sum of squares (SSE baseline), n=64. FROZEN.
__global__ __launch_bounds__(256) void norms_np_kernel(
    const float* __restrict__ x, float* __restrict__ x2) {
#pragma clang fp contract(off)
  int r = blockIdx.x * 256 + threadIdx.x;
  if (r >= NROWS) return;
  const float4* p = (const float4*)(x + (size_t)r * DD);
  float s[DD];
#pragma unroll
  for (int i = 0; i < DD / 4; ++i) {
    float4 v = p[i];
    s[4 * i + 0] = v.x * v.x;
    s[4 * i + 1] = v.y * v.y;
    s[4 * i + 2] = v.z * v.z;
    s[4 * i + 3] = v.w * v.w;
  }
  float acc[4][4];
#pragma unroll
  for (int c = 0; c < 4; ++c)
#pragma unroll
    for (int l = 0; l < 4; ++l) acc[c][l] = s[4 * c + l];
#pragma unroll
  for (int b = 1; b < 4; ++b)
#pragma unroll
    for (int c = 0; c < 4; ++c)
#pragma unroll
      for (int l = 0; l < 4; ++l)
        acc[c][l] = acc[c][l] + s[16 * b + 4 * c + l];
  float S[4];
#pragma unroll
  for (int l = 0; l < 4; ++l)
    S[l] = (acc[0][l] + acc[1][l]) + (acc[2][l] + acc[3][l]);
  x2[r] = (S[0] + S[1]) + (S[2] + S[3]);
}

// Packed compare-swap: sA=min, sB=max (u32 => (quantized key, idx) lex).
#define PSTEP(sA, sB)                       \
  do {                                      \
    unsigned lo_ = min((sA), (sB));         \
    unsigned hi_ = max((sA), (sB));         \
    (sA) = lo_; (sB) = hi_;                 \
  } while (0)

#define PBUBBLE20(S)                                              \
  do {                                                            \
    PSTEP(S##18, S##19); PSTEP(S##17, S##18); PSTEP(S##16, S##17);\
    PSTEP(S##15, S##16); PSTEP(S##14, S##15); PSTEP(S##13, S##14);\
    PSTEP(S##12, S##13); PSTEP(S##11, S##12); PSTEP(S##10, S##11);\
    PSTEP(S##9,  S##10); PSTEP(S##8,  S##9);  PSTEP(S##7,  S##8); \
    PSTEP(S##6,  S##7);  PSTEP(S##5,  S##6);  PSTEP(S##4,  S##5); \
    PSTEP(S##3,  S##4);  PSTEP(S##2,  S##3);  PSTEP(S##1,  S##2); \
    PSTEP(S##0,  S##1);                                           \
  } while (0)

#define PDECL20(S)                                                          \
  unsigned S##0 = 0xFFFFFFFFu, S##1 = 0xFFFFFFFFu, S##2 = 0xFFFFFFFFu,      \
           S##3 = 0xFFFFFFFFu, S##4 = 0xFFFFFFFFu, S##5 = 0xFFFFFFFFu,      \
           S##6 = 0xFFFFFFFFu, S##7 = 0xFFFFFFFFu, S##8 = 0xFFFFFFFFu,      \
           S##9 = 0xFFFFFFFFu, S##10 = 0xFFFFFFFFu, S##11 = 0xFFFFFFFFu,    \
           S##12 = 0xFFFFFFFFu, S##13 = 0xFFFFFFFFu, S##14 = 0xFFFFFFFFu,   \
           S##15 = 0xFFFFFFFFu, S##16 = 0xFFFFFFFFu, S##17 = 0xFFFFFFFFu,   \
           S##18 = 0xFFFFFFFFu, S##19 = 0xFFFFFFFFu;

#define PSTORE20(BASE, S, C0)                                               \
  do {                                                                      \
    pi[(BASE) + 0]  = (int)(S##0  & IMASK) + (C0);                          \
    pi[(BASE) + 1]  = (int)(S##1  & IMASK) + (C0);                          \
    pi[(BASE) + 2]  = (int)(S##2  & IMASK) + (C0);                          \
    pi[(BASE) + 3]  = (int)(S##3  & IMASK) + (C0);                          \
    pi[(BASE) + 4]  = (int)(S##4  & IMASK) + (C0);                          \
    pi[(BASE) + 5]  = (int)(S##5  & IMASK) + (C0);                          \
    pi[(BASE) + 6]  = (int)(S##6  & IMASK) + (C0);                          \
    pi[(BASE) + 7]  = (int)(S##7  & IMASK) + (C0);                          \
    pi[(BASE) + 8]  = (int)(S##8  & IMASK) + (C0);                          \
    pi[(BASE) + 9]  = (int)(S##9  & IMASK) + (C0);                          \
    pi[(BASE) + 10] = (int)(S##10 & IMASK) + (C0);                          \
    pi[(BASE) + 11] = (int)(S##11 & IMASK) + (C0);                          \
    pi[(BASE) + 12] = (int)(S##12 & IMASK) + (C0);                          \
    pi[(BASE) + 13] = (int)(S##13 & IMASK) + (C0);                          \
    pi[(BASE) + 14] = (int)(S##14 & IMASK) + (C0);                          \
    pi[(BASE) + 15] = (int)(S##15 & IMASK) + (C0);                          \
    pi[(BASE) + 16] = (int)(S##16 & IMASK) + (C0);                          \
    pi[(BASE) + 17] = (int)(S##17 & IMASK) + (C0);                          \
    pi[(BASE) + 18] = (int)(S##18 & IMASK) + (C0);                          \
    pi[(BASE) + 19] = (int)(S##19 & IMASK) + (C0);                          \
  } while (0)

// packed-fp32 dual-fma on one candidate float4 (v_pk_fma_f32 x2)
#define PK2(QF4, WLO, WHI, ACC0, ACC1)                             \
  do {                                                             \
    f32x2 qlo_ = {(QF4).x, (QF4).y};                               \
    f32x2 qhi_ = {(QF4).z, (QF4).w};                               \
    ACC0 = __builtin_elementwise_fma(qlo_, (WLO), ACC0);           \
    ACC1 = __builtin_elementwise_fma(qhi_, (WHI), ACC1);           \
  } while (0)

// Q=2 partial: thread owns rows (rb*512+tid) and (+256); one LDS read
// feeds both dots.
template <int P>
__global__ __launch_bounds__(256)
__attribute__((amdgpu_waves_per_eu(2, 2)))
void knn_partial2_kernel(
    const float* __restrict__ x, const float* __restrict__ x2,
    int* __restrict__ pi) {
  constexpr int IB = (P == 8) ? 10 : (P == 4) ? 11 : 12;
  constexpr unsigned IMASK = (1u << IB) - 1u;
  constexpr unsigned QMASK = ~IMASK;

  __shared__ float tile[TILE * DD];   // 16 KB candidate tile
  __shared__ float x2t[TILE];

  const int tid      = threadIdx.x;
  const int rb       = blockIdx.x / P;
  const int chunk    = blockIdx.x % P;
  const int base_row = rb * 512;
  const int b        = base_row >> 13;
  const int rowA     = base_row + tid;
  const int rowB     = rowA + 256;
  const int jA       = rowA & (MM - 1);
  const int jB       = jA + 256;

  const float* __restrict__ xb  = x + (size_t)b * MM * DD;
  const float* __restrict__ x2b = x2 + b * MM;

  const float4* qpA = (const float4*)(xb + (size_t)jA * DD);
  const float4* qpB = (const float4*)(xb + (size_t)jB * DD);
  float4 qa0 = qpA[0],  qa1 = qpA[1],  qa2 = qpA[2],  qa3 = qpA[3];
  float4 qa4 = qpA[4],  qa5 = qpA[5],  qa6 = qpA[6],  qa7 = qpA[7];
  float4 qa8 = qpA[8],  qa9 = qpA[9],  qa10 = qpA[10], qa11 = qpA[11];
  float4 qa12 = qpA[12], qa13 = qpA[13], qa14 = qpA[14], qa15 = qpA[15];
  float4 qb0 = qpB[0],  qb1 = qpB[1],  qb2 = qpB[2],  qb3 = qpB[3];
  float4 qb4 = qpB[4],  qb5 = qpB[5],  qb6 = qpB[6],  qb7 = qpB[7];
  float4 qb8 = qpB[8],  qb9 = qpB[9],  qb10 = qpB[10], qb11 = qpB[11];
  float4 qb12 = qpB[12], qb13 = qpB[13], qb14 = qpB[14], qb15 = qpB[15];

  PDECL20(sa)
  PDECL20(sb)

  const int C  = MM / P;
  const int c0 = chunk * C;

  for (int ts = c0; ts < c0 + C; ts += TILE) {
    __syncthreads();
    {
      const float4* gsrc = (const float4*)(xb + (size_t)ts * DD);
      float4* lds4 = (float4*)tile;
#pragma unroll
      for (int u = 0; u < 4; ++u) lds4[tid + 256 * u] = gsrc[tid + 256 * u];
      if (tid < TILE / 4)
        ((float4*)x2t)[tid] = ((const float4*)(x2b + ts))[tid];
    }
    __syncthreads();

#pragma unroll 1
    for (int t = 0; t < TILE; ++t) {
      const float4* cp = (const float4*)(tile + t * DD);
      f32x2 aA0 = {0.f, 0.f}, aA1 = {0.f, 0.f};
      f32x2 aB0 = {0.f, 0.f}, aB1 = {0.f, 0.f};
      {
        float4 w;
        f32x2 wlo, whi;
#define LOADW(I)  w = cp[I]; wlo = (f32x2){w.x, w.y}; whi = (f32x2){w.z, w.w}
        LOADW(0);  PK2(qa0,  wlo, whi, aA0, aA1); PK2(qb0,  wlo, whi, aB0, aB1);
        LOADW(1);  PK2(qa1,  wlo, whi, aA0, aA1); PK2(qb1,  wlo, whi, aB0, aB1);
        LOADW(2);  PK2(qa2,  wlo, whi, aA0, aA1); PK2(qb2,  wlo, whi, aB0, aB1);
        LOADW(3);  PK2(qa3,  wlo, whi, aA0, aA1); PK2(qb3,  wlo, whi, aB0, aB1);
        LOADW(4);  PK2(qa4,  wlo, whi, aA0, aA1); PK2(qb4,  wlo, whi, aB0, aB1);
        LOADW(5);  PK2(qa5,  wlo, whi, aA0, aA1); PK2(qb5,  wlo, whi, aB0, aB1);
        LOADW(6);  PK2(qa6,  wlo, whi, aA0, aA1); PK2(qb6,  wlo, whi, aB0, aB1);
        LOADW(7);  PK2(qa7,  wlo, whi, aA0, aA1); PK2(qb7,  wlo, whi, aB0, aB1);
        LOADW(8);  PK2(qa8,  wlo, whi, aA0, aA1); PK2(qb8,  wlo, whi, aB0, aB1);
        LOADW(9);  PK2(qa9,  wlo, whi, aA0, aA1); PK2(qb9,  wlo, whi, aB0, aB1);
        LOADW(10); PK2(qa10, wlo, whi, aA0, aA1); PK2(qb10, wlo, whi, aB0, aB1);
        LOADW(11); PK2(qa11, wlo, whi, aA0, aA1); PK2(qb11, wlo, whi, aB0, aB1);
        LOADW(12); PK2(qa12, wlo, whi, aA0, aA1); PK2(qb12, wlo, whi, aB0, aB1);
        LOADW(13); PK2(qa13, wlo, whi, aA0, aA1); PK2(qb13, wlo, whi, aB0, aB1);
        LOADW(14); PK2(qa14, wlo, whi, aA0, aA1); PK2(qb14, wlo, whi, aB0, aB1);
        LOADW(15); PK2(qa15, wlo, whi, aA0, aA1); PK2(qb15, wlo, whi, aB0, aB1);
#undef LOADW
      }
      float x2c = x2t[t];
      f32x2 rA = aA0 + aA1;
      f32x2 rB = aB0 + aB1;
      float dotA = rA.x + rA.y;
      float dotB = rB.x + rB.y;
      float keyA = fmaf(-2.f, dotA, x2c);
      float keyB = fmaf(-2.f, dotB, x2c);

      int kiA = __float_as_int(keyA);
      unsigned monoA = (unsigned)kiA ^ ((unsigned)(kiA >> 31) | 0x80000000u);
      unsigned pkA = (monoA & QMASK) | (unsigned)(ts - c0 + t);
      sa19 = min(sa19, pkA);
      PBUBBLE20(sa);

      int kiB = __float_as_int(keyB);
      unsigned monoB = (unsigned)kiB ^ ((unsigned)(kiB >> 31) | 0x80000000u);
      unsigned pkB = (monoB & QMASK) | (unsigned)(ts - c0 + t);
      sb19 = min(sb19, pkB);
      PBUBBLE20(sb);
    }
  }

  size_t baseA = ((size_t)rowA * P + chunk) * TK;
  size_t baseB = ((size_t)rowB * P + chunk) * TK;
  PSTORE20(baseA, sa, c0);
  PSTORE20(baseB, sb, c0);
}

// Q=1 packed partial (R14-proven), workspace fallback.
template <int P>
__global__ __launch_bounds__(256)
__attribute__((amdgpu_waves_per_eu(2, 2)))
void knn_partial_q1_kernel(
    const float* __restrict__ x, const float* __restrict__ x2,
    int* __restrict__ pi) {
  constexpr int IB = (P == 8) ? 10 : (P == 4) ? 11 : (P == 2) ? 12 : 13;
  constexpr unsigned IMASK = (1u << IB) - 1u;
  constexpr unsigned QMASK = ~IMASK;

  __shared__ float tile[TILE * DD];
  __shared__ float x2t[TILE];

  const int tid   = threadIdx.x;
  const int rb    = blockIdx.x / P;
  const int chunk = blockIdx.x % P;
  const int b     = rb >> 5;
  const int row   = rb * 256 + tid;
  const int j     = row - b * MM;

  const float* __restrict__ xb  = x + (size_t)b * MM * DD;
  const float* __restrict__ x2b = x2 + b * MM;

  const float4* qp = (const float4*)(xb + (size_t)j * DD);
  float4 q0 = qp[0],  q1 = qp[1],  q2 = qp[2],  q3 = qp[3];
  float4 q4 = qp[4],  q5 = qp[5],  q6 = qp[6],  q7 = qp[7];
  float4 q8 = qp[8],  q9 = qp[9],  q10 = qp[10], q11 = qp[11];
  float4 q12 = qp[12], q13 = qp[13], q14 = qp[14], q15 = qp[15];

  PDECL20(s)

  const int C  = MM / P;
  const int c0 = chunk * C;

  for (int ts = c0; ts < c0 + C; ts += TILE) {
    __syncthreads();
    {
      const float4* gsrc = (const float4*)(xb + (size_t)ts * DD);
      float4* lds4 = (float4*)tile;
#pragma unroll
      for (int u = 0; u < 4; ++u) lds4[tid + 256 * u] = gsrc[tid + 256 * u];
      if (tid < TILE / 4)
        ((float4*)x2t)[tid] = ((const float4*)(x2b + ts))[tid];
    }
    __syncthreads();

#pragma unroll 2
    for (int t = 0; t < TILE; ++t) {
      const float4* cp = (const float4*)(tile + t * DD);
      f32x2 a0 = {0.f, 0.f}, a1 = {0.f, 0.f};
      {
        float4 w;
        f32x2 wlo, whi;
#define LOADW(I)  w = cp[I]; wlo = (f32x2){w.x, w.y}; whi = (f32x2){w.z, w.w}
        LOADW(0);  PK2(q0,  wlo, whi, a0, a1);
        LOADW(1);  PK2(q1,  wlo, whi, a0, a1);
        LOADW(2);  PK2(q2,  wlo, whi, a0, a1);
        LOADW(3);  PK2(q3,  wlo, whi, a0, a1);
        LOADW(4);  PK2(q4,  wlo, whi, a0, a1);
        LOADW(5);  PK2(q5,  wlo, whi, a0, a1);
        LOADW(6);  PK2(q6,  wlo, whi, a0, a1);
        LOADW(7);  PK2(q7,  wlo, whi, a0, a1);
        LOADW(8);  PK2(q8,  wlo, whi, a0, a1);
        LOADW(9);  PK2(q9,  wlo, whi, a0, a1);
        LOADW(10); PK2(q10, wlo, whi, a0, a1);
        LOADW(11); PK2(q11, wlo, whi, a0, a1);
        LOADW(12); PK2(q12, wlo, whi, a0, a1);
        LOADW(13); PK2(q13, wlo, whi, a0, a1);
        LOADW(14); PK2(q14, wlo, whi, a0, a1);
        LOADW(15); PK2(q15, wlo, whi, a0, a1);
#undef LOADW
      }
      f32x2 rr = a0 + a1;
      float dot = rr.x + rr.y;
      float key = fmaf(-2.f, dot, x2t[t]);

      int ki = __float_as_int(key);
      unsigned mono = (unsigned)ki ^ ((unsigned)(ki >> 31) | 0x80000000u);
      unsigned pk = (mono & QMASK) | (unsigned)(ts - c0 + t);
      s19 = min(s19, pk);
      PBUBBLE20(s);
    }
  }

  size_t base = ((size_t)row * P + chunk) * TK;
  PSTORE20(base, s, c0);
}

// FROZEN-numerics einsum block: per-product rounding then reversed adds.
#define EBLK(QA, QB, QC, QD, W0, W1, W2, W3)                                  \
  do {                                                                        \
    v0 = (QA).x * (W0).x +                                                    \
         ((QB).x * (W1).x + ((QC).x * (W2).x + ((QD).x * (W3).x + v0)));      \
    v1 = (QA).y * (W0).y +                                                    \
         ((QB).y * (W1).y + ((QC).y * (W2).y + ((QD).y * (W3).y + v1)));      \
    v2 = (QA).z * (W0).z +                                                    \
         ((QB).z * (W1).z + ((QC).z * (W2).z + ((QD).z * (W3).z + v2)));      \
    v3 = (QA).w * (W0).w +                                                    \
         ((QB).w * (W1).w + ((QC).w * (W2).w + ((QD).w * (W3).w + v3)));      \
  } while (0)

template <int P>
__global__ __launch_bounds__(256)
__attribute__((amdgpu_waves_per_eu(2, 2)))
void knn_rescore_kernel(
    const float* __restrict__ x, const float* __restrict__ x2,
    const int* __restrict__ pi,
    int* __restrict__ src, int* __restrict__ dst) {
#pragma clang fp contract(off)
  int r = blockIdx.x * 256 + threadIdx.x;
  if (r >= NROWS) return;
  const int b = r >> 13;
  const int j = r & (MM - 1);
  const float* __restrict__ xb = x + (size_t)b * MM * DD;
  const float x2j = x2[r];

  const float4* qp = (const float4*)(xb + (size_t)j * DD);
  float4 q0 = qp[0],  q1 = qp[1],  q2 = qp[2],  q3 = qp[3];
  float4 q4 = qp[4],  q5 = qp[5],  q6 = qp[6],  q7 = qp[7];
  float4 q8 = qp[8],  q9 = qp[9],  q10 = qp[10], q11 = qp[11];
  float4 q12 = qp[12], q13 = qp[13], q14 = qp[14], q15 = qp[15];

  float bd[KK];
  int   bi[KK];
#pragma unroll
  for (int t = 0; t < KK; ++t) {
    bd[t] = __builtin_inff();
    bi[t] = 0x7fffffff;
  }

  const int CAND = P * TK;
  size_t base = (size_t)r * CAND;

  for (int t = 0; t < CAND; ++t) {
    int c = pi[base + t];
    const float4* pp = (const float4*)(xb + (size_t)c * DD);
    // FROZEN numerics: einsum baseline-SSE reversed muladd chain.
    float v0 = 0.f, v1 = 0.f, v2 = 0.f, v3 = 0.f;
    {
      float4 w0 = pp[0], w1 = pp[1], w2 = pp[2], w3 = pp[3];
      EBLK(q0, q1, q2, q3, w0, w1, w2, w3);
    }
    {
      float4 w0 = pp[4], w1 = pp[5], w2 = pp[6], w3 = pp[7];
      EBLK(q4, q5, q6, q7, w0, w1, w2, w3);
    }
    {
      float4 w0 = pp[8], w1 = pp[9], w2 = pp[10], w3 = pp[11];
      EBLK(q8, q9, q10, q11, w0, w1, w2, w3);
    }
    {
      float4 w0 = pp[12], w1 = pp[13], w2 = pp[14], w3 = pp[15];
      EBLK(q12, q13, q14, q15, w0, w1, w2, w3);
    }
    float dotf = (v0 + v1) + (v2 + v3);
    float s  = x2j + x2[b * MM + c];
    float tm = 2.0f * dotf;
    float d2 = s - tm;

    bool lt = (d2 < bd[KK - 1]) ||
              (d2 == bd[KK - 1] && c < bi[KK - 1]);
    if (lt) {
      bd[KK - 1] = d2;
      bi[KK - 1] = c;
#pragma unroll
      for (int t2 = KK - 1; t2 > 0; --t2) {
        bool sw = (bd[t2] < bd[t2 - 1]) ||
                  (bd[t2] == bd[t2 - 1] && bi[t2] < bi[t2 - 1]);
        float dlo = sw ? bd[t2] : bd[t2 - 1];
        float dhi = sw ? bd[t2 - 1] : bd[t2];
        int   ilo = sw ? bi[t2] : bi[t2 - 1];
        int   ihi = sw ? bi[t2 - 1] : bi[t2];
        bd[t2 - 1] = dlo; bd[t2] = dhi;
        bi[t2 - 1] = ilo; bi[t2] = ihi;
      }
    }
  }

#pragma unroll
  for (int t = 0; t < KK; ++t) {
    src[(size_t)r * KK + t] = b * MM + bi[t];
    dst[(size_t)r * KK + t] = r;
  }
}

template <int P, bool Q2>
static void launch_all(const float* x, int* out, void* d_ws, hipStream_t stream) {
  char* ws = (char*)d_ws;
  float* x2 = (float*)ws;
  int*   pi = (int*)(ws + (size_t)NROWS * sizeof(float));

  int* src = out;
  int* dst = out + (size_t)NROWS * KK;

  norms_np_kernel<<<NROWS / 256, 256, 0, stream>>>(x, x2);
  if (Q2) {
    knn_partial2_kernel<P><<<(NROWS / 512) * P, 256, 0, stream>>>(x, x2, pi);
  } else {
    knn_partial_q1_kernel<P><<<(NROWS / 256) * P, 256, 0, stream>>>(x, x2, pi);
  }
  knn_rescore_kernel<P><<<NROWS / 256, 256, 0, stream>>>(x, x2, pi, src, dst);
}

extern "C" void kernel_launch(void* const* d_in, const int* in_sizes, int n_in,
                              void* d_out, int out_size, void* d_ws, size_t ws_size,
                              hipStream_t stream) {
  const float* x = (const float*)d_in[0];
  int* out = (int*)d_out;

  auto need = [](int P) {
    return (size_t)NROWS * sizeof(float) +
           (size_t)NROWS * P * TK * sizeof(int);
  };

  if (ws_size >= need(8)) {
    launch_all<8, true>(x, out, d_ws, stream);   // Q=2, P=8 (R13 proved ws fits)
  } else if (ws_size >= need(4)) {
    launch_all<4, true>(x, out, d_ws, stream);   // Q=2, P=4
  } else if (ws_size >= need(2)) {
    launch_all<2, false>(x, out, d_ws, stream);
  } else {
    launch_all<1, false>(x, out, d_ws, stream);
  }
}

// Round 16
// 1008.706 us; speedup vs baseline: 5.4516x; 1.2371x over previous
//
#include <hip/hip_runtime.h>

// KNNGraph bruteforce-blas, euclidean, k=16, include self.
// x: (N=4, M=8192, D=64) fp32. Output: int32 src[N*M*K] then dst[N*M*K].
//
// VALIDATED reference model (R9, absmax=0 — numerics FROZEN):
//   x2  = np.sum(x*x,-1): squares rounded per-element, FLOAT_pairwise_sum
//         n=64 NPY_SIMD path: 4 vec accs (vstep=4), serial blocks,
//         combine (r0+r1)+(r2+r3), double-hadd (S0+S1)+(S2+S3).
//   dot = np.einsum baseline-SSE: per-16 block REVERSED muladd chain
//         v_l = p0l+(p1l+(p2l+(p3l+v_l))), double-hadd (v0+v1)+(v2+v3).
//   d2  = fl(fl(x2j+x2c) - fl(2*dot)); stable ties by lower index.
//
// R16: (1) partial reads candidates DIRECT from global (wave-uniform addr,
// L1 broadcast) — kills the LDS pipe cost (~550 us of broadcast ds_reads
// moving 16 B each). (2) rescore parallelized 4x: 4 threads/row rescore 40
// shortlist entries each (frozen numerics), lex top-16 in registers, 4-way
// sorted merge via LDS. Selection stays packed-u32 (R14) + Q=2 (R15).

#define MM 8192
#define NN 4
#define DD 64
#define KK 16
#define TK 20            // stage-A keep per chunk (16 + 4 safety margin)
#define TILE 64          // (LDS fallback path only)
#define NROWS (NN * MM)  // 32768

typedef float f32x2 __attribute__((ext_vector_type(2)));

// numpy SIMD pairwise sum of squares (SSE baseline), n=64. FROZEN.
__global__ __launch_bounds__(256) void norms_np_kernel(
    const float* __restrict__ x, float* __restrict__ x2) {
#pragma clang fp contract(off)
  int r = blockIdx.x * 256 + threadIdx.x;
  if (r >= NROWS) return;
  const float4* p = (const float4*)(x + (size_t)r * DD);
  float s[DD];
#pragma unroll
  for (int i = 0; i < DD / 4; ++i) {
    float4 v = p[i];
    s[4 * i + 0] = v.x * v.x;
    s[4 * i + 1] = v.y * v.y;
    s[4 * i + 2] = v.z * v.z;
    s[4 * i + 3] = v.w * v.w;
  }
  float acc[4][4];
#pragma unroll
  for (int c = 0; c < 4; ++c)
#pragma unroll
    for (int l = 0; l < 4; ++l) acc[c][l] = s[4 * c + l];
#pragma unroll
  for (int b = 1; b < 4; ++b)
#pragma unroll
    for (int c = 0; c < 4; ++c)
#pragma unroll
      for (int l = 0; l < 4; ++l)
        acc[c][l] = acc[c][l] + s[16 * b + 4 * c + l];
  float S[4];
#pragma unroll
  for (int l = 0; l < 4; ++l)
    S[l] = (acc[0][l] + acc[1][l]) + (acc[2][l] + acc[3][l]);
  x2[r] = (S[0] + S[1]) + (S[2] + S[3]);
}

// Packed compare-swap: sA=min, sB=max (u32 => (quantized key, idx) lex).
#define PSTEP(sA, sB)                       \
  do {                                      \
    unsigned lo_ = min((sA), (sB));         \
    unsigned hi_ = max((sA), (sB));         \
    (sA) = lo_; (sB) = hi_;                 \
  } while (0)

#define PBUBBLE20(S)                                              \
  do {                                                            \
    PSTEP(S##18, S##19); PSTEP(S##17, S##18); PSTEP(S##16, S##17);\
    PSTEP(S##15, S##16); PSTEP(S##14, S##15); PSTEP(S##13, S##14);\
    PSTEP(S##12, S##13); PSTEP(S##11, S##12); PSTEP(S##10, S##11);\
    PSTEP(S##9,  S##10); PSTEP(S##8,  S##9);  PSTEP(S##7,  S##8); \
    PSTEP(S##6,  S##7);  PSTEP(S##5,  S##6);  PSTEP(S##4,  S##5); \
    PSTEP(S##3,  S##4);  PSTEP(S##2,  S##3);  PSTEP(S##1,  S##2); \
    PSTEP(S##0,  S##1);                                           \
  } while (0)

#define PDECL20(S)                                                          \
  unsigned S##0 = 0xFFFFFFFFu, S##1 = 0xFFFFFFFFu, S##2 = 0xFFFFFFFFu,      \
           S##3 = 0xFFFFFFFFu, S##4 = 0xFFFFFFFFu, S##5 = 0xFFFFFFFFu,      \
           S##6 = 0xFFFFFFFFu, S##7 = 0xFFFFFFFFu, S##8 = 0xFFFFFFFFu,      \
           S##9 = 0xFFFFFFFFu, S##10 = 0xFFFFFFFFu, S##11 = 0xFFFFFFFFu,    \
           S##12 = 0xFFFFFFFFu, S##13 = 0xFFFFFFFFu, S##14 = 0xFFFFFFFFu,   \
           S##15 = 0xFFFFFFFFu, S##16 = 0xFFFFFFFFu, S##17 = 0xFFFFFFFFu,   \
           S##18 = 0xFFFFFFFFu, S##19 = 0xFFFFFFFFu;

#define PSTORE20(BASE, S, C0)                                               \
  do {                                                                      \
    pi[(BASE) + 0]  = (int)(S##0  & IMASK) + (C0);                          \
    pi[(BASE) + 1]  = (int)(S##1  & IMASK) + (C0);                          \
    pi[(BASE) + 2]  = (int)(S##2  & IMASK) + (C0);                          \
    pi[(BASE) + 3]  = (int)(S##3  & IMASK) + (C0);                          \
    pi[(BASE) + 4]  = (int)(S##4  & IMASK) + (C0);                          \
    pi[(BASE) + 5]  = (int)(S##5  & IMASK) + (C0);                          \
    pi[(BASE) + 6]  = (int)(S##6  & IMASK) + (C0);                          \
    pi[(BASE) + 7]  = (int)(S##7  & IMASK) + (C0);                          \
    pi[(BASE) + 8]  = (int)(S##8  & IMASK) + (C0);                          \
    pi[(BASE) + 9]  = (int)(S##9  & IMASK) + (C0);                          \
    pi[(BASE) + 10] = (int)(S##10 & IMASK) + (C0);                          \
    pi[(BASE) + 11] = (int)(S##11 & IMASK) + (C0);                          \
    pi[(BASE) + 12] = (int)(S##12 & IMASK) + (C0);                          \
    pi[(BASE) + 13] = (int)(S##13 & IMASK) + (C0);                          \
    pi[(BASE) + 14] = (int)(S##14 & IMASK) + (C0);                          \
    pi[(BASE) + 15] = (int)(S##15 & IMASK) + (C0);                          \
    pi[(BASE) + 16] = (int)(S##16 & IMASK) + (C0);                          \
    pi[(BASE) + 17] = (int)(S##17 & IMASK) + (C0);                          \
    pi[(BASE) + 18] = (int)(S##18 & IMASK) + (C0);                          \
    pi[(BASE) + 19] = (int)(S##19 & IMASK) + (C0);                          \
  } while (0)

// packed-fp32 dual-fma on one candidate float4 (v_pk_fma_f32 x2)
#define PK2(QF4, WLO, WHI, ACC0, ACC1)                             \
  do {                                                             \
    f32x2 qlo_ = {(QF4).x, (QF4).y};                               \
    f32x2 qhi_ = {(QF4).z, (QF4).w};                               \
    ACC0 = __builtin_elementwise_fma(qlo_, (WLO), ACC0);           \
    ACC1 = __builtin_elementwise_fma(qhi_, (WHI), ACC1);           \
  } while (0)

// Q=2 partial, NO LDS: candidates read direct from global at wave-uniform
// addresses (L1 broadcast). One read feeds both owned rows.
template <int P>
__global__ __launch_bounds__(256)
__attribute__((amdgpu_waves_per_eu(2, 2)))
void knn_partial2_kernel(
    const float* __restrict__ x, const float* __restrict__ x2,
    int* __restrict__ pi) {
  constexpr int IB = (P == 8) ? 10 : (P == 4) ? 11 : 12;
  constexpr unsigned IMASK = (1u << IB) - 1u;
  constexpr unsigned QMASK = ~IMASK;

  const int tid      = threadIdx.x;
  const int rb       = blockIdx.x / P;
  const int chunk    = blockIdx.x % P;
  const int base_row = rb * 512;
  const int b        = base_row >> 13;
  const int rowA     = base_row + tid;
  const int rowB     = rowA + 256;
  const int jA       = rowA & (MM - 1);
  const int jB       = jA + 256;

  const float* __restrict__ xb  = x + (size_t)b * MM * DD;
  const float* __restrict__ x2b = x2 + b * MM;

  const float4* qpA = (const float4*)(xb + (size_t)jA * DD);
  const float4* qpB = (const float4*)(xb + (size_t)jB * DD);
  float4 qa0 = qpA[0],  qa1 = qpA[1],  qa2 = qpA[2],  qa3 = qpA[3];
  float4 qa4 = qpA[4],  qa5 = qpA[5],  qa6 = qpA[6],  qa7 = qpA[7];
  float4 qa8 = qpA[8],  qa9 = qpA[9],  qa10 = qpA[10], qa11 = qpA[11];
  float4 qa12 = qpA[12], qa13 = qpA[13], qa14 = qpA[14], qa15 = qpA[15];
  float4 qb0 = qpB[0],  qb1 = qpB[1],  qb2 = qpB[2],  qb3 = qpB[3];
  float4 qb4 = qpB[4],  qb5 = qpB[5],  qb6 = qpB[6],  qb7 = qpB[7];
  float4 qb8 = qpB[8],  qb9 = qpB[9],  qb10 = qpB[10], qb11 = qpB[11];
  float4 qb12 = qpB[12], qb13 = qpB[13], qb14 = qpB[14], qb15 = qpB[15];

  PDECL20(sa)
  PDECL20(sb)

  const int C  = MM / P;
  const int c0 = chunk * C;

#pragma unroll 1
  for (int c = c0; c < c0 + C; ++c) {
    const float4* cp = (const float4*)(xb + (size_t)c * DD);  // uniform addr
    float x2c = x2b[c];
    f32x2 aA0 = {0.f, 0.f}, aA1 = {0.f, 0.f};
    f32x2 aB0 = {0.f, 0.f}, aB1 = {0.f, 0.f};
    {
      float4 w;
      f32x2 wlo, whi;
#define LOADW(I)  w = cp[I]; wlo = (f32x2){w.x, w.y}; whi = (f32x2){w.z, w.w}
      LOADW(0);  PK2(qa0,  wlo, whi, aA0, aA1); PK2(qb0,  wlo, whi, aB0, aB1);
      LOADW(1);  PK2(qa1,  wlo, whi, aA0, aA1); PK2(qb1,  wlo, whi, aB0, aB1);
      LOADW(2);  PK2(qa2,  wlo, whi, aA0, aA1); PK2(qb2,  wlo, whi, aB0, aB1);
      LOADW(3);  PK2(qa3,  wlo, whi, aA0, aA1); PK2(qb3,  wlo, whi, aB0, aB1);
      LOADW(4);  PK2(qa4,  wlo, whi, aA0, aA1); PK2(qb4,  wlo, whi, aB0, aB1);
      LOADW(5);  PK2(qa5,  wlo, whi, aA0, aA1); PK2(qb5,  wlo, whi, aB0, aB1);
      LOADW(6);  PK2(qa6,  wlo, whi, aA0, aA1); PK2(qb6,  wlo, whi, aB0, aB1);
      LOADW(7);  PK2(qa7,  wlo, whi, aA0, aA1); PK2(qb7,  wlo, whi, aB0, aB1);
      LOADW(8);  PK2(qa8,  wlo, whi, aA0, aA1); PK2(qb8,  wlo, whi, aB0, aB1);
      LOADW(9);  PK2(qa9,  wlo, whi, aA0, aA1); PK2(qb9,  wlo, whi, aB0, aB1);
      LOADW(10); PK2(qa10, wlo, whi, aA0, aA1); PK2(qb10, wlo, whi, aB0, aB1);
      LOADW(11); PK2(qa11, wlo, whi, aA0, aA1); PK2(qb11, wlo, whi, aB0, aB1);
      LOADW(12); PK2(qa12, wlo, whi, aA0, aA1); PK2(qb12, wlo, whi, aB0, aB1);
      LOADW(13); PK2(qa13, wlo, whi, aA0, aA1); PK2(qb13, wlo, whi, aB0, aB1);
      LOADW(14); PK2(qa14, wlo, whi, aA0, aA1); PK2(qb14, wlo, whi, aB0, aB1);
      LOADW(15); PK2(qa15, wlo, whi, aA0, aA1); PK2(qb15, wlo, whi, aB0, aB1);
#undef LOADW
    }
    f32x2 rA = aA0 + aA1;
    f32x2 rB = aB0 + aB1;
    float dotA = rA.x + rA.y;
    float dotB = rB.x + rB.y;
    float keyA = fmaf(-2.f, dotA, x2c);
    float keyB = fmaf(-2.f, dotB, x2c);

    int kiA = __float_as_int(keyA);
    unsigned monoA = (unsigned)kiA ^ ((unsigned)(kiA >> 31) | 0x80000000u);
    unsigned pkA = (monoA & QMASK) | (unsigned)(c - c0);
    sa19 = min(sa19, pkA);
    PBUBBLE20(sa);

    int kiB = __float_as_int(keyB);
    unsigned monoB = (unsigned)kiB ^ ((unsigned)(kiB >> 31) | 0x80000000u);
    unsigned pkB = (monoB & QMASK) | (unsigned)(c - c0);
    sb19 = min(sb19, pkB);
    PBUBBLE20(sb);
  }

  size_t baseA = ((size_t)rowA * P + chunk) * TK;
  size_t baseB = ((size_t)rowB * P + chunk) * TK;
  PSTORE20(baseA, sa, c0);
  PSTORE20(baseB, sb, c0);
}

// Q=1 packed partial (LDS path, R14-proven) — workspace fallback only.
template <int P>
__global__ __launch_bounds__(256)
__attribute__((amdgpu_waves_per_eu(2, 2)))
void knn_partial_q1_kernel(
    const float* __restrict__ x, const float* __restrict__ x2,
    int* __restrict__ pi) {
  constexpr int IB = (P == 8) ? 10 : (P == 4) ? 11 : (P == 2) ? 12 : 13;
  constexpr unsigned IMASK = (1u << IB) - 1u;
  constexpr unsigned QMASK = ~IMASK;

  __shared__ float tile[TILE * DD];
  __shared__ float x2t[TILE];

  const int tid   = threadIdx.x;
  const int rb    = blockIdx.x / P;
  const int chunk = blockIdx.x % P;
  const int b     = rb >> 5;
  const int row   = rb * 256 + tid;
  const int j     = row - b * MM;

  const float* __restrict__ xb  = x + (size_t)b * MM * DD;
  const float* __restrict__ x2b = x2 + b * MM;

  const float4* qp = (const float4*)(xb + (size_t)j * DD);
  float4 q0 = qp[0],  q1 = qp[1],  q2 = qp[2],  q3 = qp[3];
  float4 q4 = qp[4],  q5 = qp[5],  q6 = qp[6],  q7 = qp[7];
  float4 q8 = qp[8],  q9 = qp[9],  q10 = qp[10], q11 = qp[11];
  float4 q12 = qp[12], q13 = qp[13], q14 = qp[14], q15 = qp[15];

  PDECL20(s)

  const int C  = MM / P;
  const int c0 = chunk * C;

  for (int ts = c0; ts < c0 + C; ts += TILE) {
    __syncthreads();
    {
      const float4* gsrc = (const float4*)(xb + (size_t)ts * DD);
      float4* lds4 = (float4*)tile;
#pragma unroll
      for (int u = 0; u < 4; ++u) lds4[tid + 256 * u] = gsrc[tid + 256 * u];
      if (tid < TILE / 4)
        ((float4*)x2t)[tid] = ((const float4*)(x2b + ts))[tid];
    }
    __syncthreads();

#pragma unroll 2
    for (int t = 0; t < TILE; ++t) {
      const float4* cp = (const float4*)(tile + t * DD);
      f32x2 a0 = {0.f, 0.f}, a1 = {0.f, 0.f};
      {
        float4 w;
        f32x2 wlo, whi;
#define LOADW(I)  w = cp[I]; wlo = (f32x2){w.x, w.y}; whi = (f32x2){w.z, w.w}
        LOADW(0);  PK2(q0,  wlo, whi, a0, a1);
        LOADW(1);  PK2(q1,  wlo, whi, a0, a1);
        LOADW(2);  PK2(q2,  wlo, whi, a0, a1);
        LOADW(3);  PK2(q3,  wlo, whi, a0, a1);
        LOADW(4);  PK2(q4,  wlo, whi, a0, a1);
        LOADW(5);  PK2(q5,  wlo, whi, a0, a1);
        LOADW(6);  PK2(q6,  wlo, whi, a0, a1);
        LOADW(7);  PK2(q7,  wlo, whi, a0, a1);
        LOADW(8);  PK2(q8,  wlo, whi, a0, a1);
        LOADW(9);  PK2(q9,  wlo, whi, a0, a1);
        LOADW(10); PK2(q10, wlo, whi, a0, a1);
        LOADW(11); PK2(q11, wlo, whi, a0, a1);
        LOADW(12); PK2(q12, wlo, whi, a0, a1);
        LOADW(13); PK2(q13, wlo, whi, a0, a1);
        LOADW(14); PK2(q14, wlo, whi, a0, a1);
        LOADW(15); PK2(q15, wlo, whi, a0, a1);
#undef LOADW
      }
      f32x2 rr = a0 + a1;
      float dot = rr.x + rr.y;
      float key = fmaf(-2.f, dot, x2t[t]);

      int ki = __float_as_int(key);
      unsigned mono = (unsigned)ki ^ ((unsigned)(ki >> 31) | 0x80000000u);
      unsigned pk = (mono & QMASK) | (unsigned)(ts - c0 + t);
      s19 = min(s19, pk);
      PBUBBLE20(s);
    }
  }

  size_t base = ((size_t)row * P + chunk) * TK;
  PSTORE20(base, s, c0);
}

// FROZEN-numerics einsum block: per-product rounding then reversed adds.
#define EBLK(QA, QB, QC, QD, W0, W1, W2, W3)                                  \
  do {                                                                        \
    v0 = (QA).x * (W0).x +                                                    \
         ((QB).x * (W1).x + ((QC).x * (W2).x + ((QD).x * (W3).x + v0)));      \
    v1 = (QA).y * (W0).y +                                                    \
         ((QB).y * (W1).y + ((QC).y * (W2).y + ((QD).y * (W3).y + v1)));      \
    v2 = (QA).z * (W0).z +                                                    \
         ((QB).z * (W1).z + ((QC).z * (W2).z + ((QD).z * (W3).z + v2)));      \
    v3 = (QA).w * (W0).w +                                                    \
         ((QB).w * (W1).w + ((QC).w * (W2).w + ((QD).w * (W3).w + v3)));      \
  } while (0)

// Lexicographic (d2, idx) compare-swap (strict: stable).
#define LBSTEP(dA, iA, dB, iB)                                     \
  do {                                                             \
    bool s_ = ((dB) < (dA)) || ((dB) == (dA) && (iB) < (iA));      \
    float tl_ = s_ ? (dB) : (dA);                                  \
    float th_ = s_ ? (dA) : (dB);                                  \
    int   jl_ = s_ ? (iB) : (iA);                                  \
    int   jh_ = s_ ? (iA) : (iB);                                  \
    (dA) = tl_; (dB) = th_; (iA) = jl_; (iB) = jh_;                \
  } while (0)

// 4x-parallel rescore: 4 threads/row (wave = sub-list), exact frozen key,
// local lex top-16, then 4-way sorted merge via LDS by wave 0.
template <int P>
__global__ __launch_bounds__(256) void knn_rescore4_kernel(
    const float* __restrict__ x, const float* __restrict__ x2,
    const int* __restrict__ pi,
    int* __restrict__ src, int* __restrict__ dst) {
#pragma clang fp contract(off)
  constexpr int CAND = P * TK;
  constexpr int LPT  = CAND / 4;
  __shared__ uint2 ls[4][16][64];   // [sub][slot][row-lane] = 32 KB

  const int tid  = threadIdx.x;
  const int lane = tid & 63;
  const int sub  = tid >> 6;
  const int r    = blockIdx.x * 64 + lane;
  const int b    = r >> 13;
  const int j    = r & (MM - 1);
  const float* __restrict__ xb = x + (size_t)b * MM * DD;
  const float x2j = x2[r];

  const float4* qp = (const float4*)(xb + (size_t)j * DD);
  float4 q0 = qp[0],  q1 = qp[1],  q2 = qp[2],  q3 = qp[3];
  float4 q4 = qp[4],  q5 = qp[5],  q6 = qp[6],  q7 = qp[7];
  float4 q8 = qp[8],  q9 = qp[9],  q10 = qp[10], q11 = qp[11];
  float4 q12 = qp[12], q13 = qp[13], q14 = qp[14], q15 = qp[15];

  const float INF = __builtin_inff();
  float e0 = INF, e1 = INF, e2 = INF, e3 = INF, e4 = INF, e5 = INF,
        e6 = INF, e7 = INF, e8 = INF, e9 = INF, e10 = INF, e11 = INF,
        e12 = INF, e13 = INF, e14 = INF, e15 = INF;
  int n0 = 0x7fffffff, n1 = 0x7fffffff, n2 = 0x7fffffff, n3 = 0x7fffffff,
      n4 = 0x7fffffff, n5 = 0x7fffffff, n6 = 0x7fffffff, n7 = 0x7fffffff,
      n8 = 0x7fffffff, n9 = 0x7fffffff, n10 = 0x7fffffff, n11 = 0x7fffffff,
      n12 = 0x7fffffff, n13 = 0x7fffffff, n14 = 0x7fffffff, n15 = 0x7fffffff;

  size_t base = (size_t)r * CAND + (size_t)sub * LPT;

  for (int t = 0; t < LPT; ++t) {
    int c = pi[base + t];
    const float4* pp = (const float4*)(xb + (size_t)c * DD);
    // FROZEN numerics: einsum baseline-SSE reversed muladd chain.
    float v0 = 0.f, v1 = 0.f, v2 = 0.f, v3 = 0.f;
    {
      float4 w0 = pp[0], w1 = pp[1], w2 = pp[2], w3 = pp[3];
      EBLK(q0, q1, q2, q3, w0, w1, w2, w3);
    }
    {
      float4 w0 = pp[4], w1 = pp[5], w2 = pp[6], w3 = pp[7];
      EBLK(q4, q5, q6, q7, w0, w1, w2, w3);
    }
    {
      float4 w0 = pp[8], w1 = pp[9], w2 = pp[10], w3 = pp[11];
      EBLK(q8, q9, q10, q11, w0, w1, w2, w3);
    }
    {
      float4 w0 = pp[12], w1 = pp[13], w2 = pp[14], w3 = pp[15];
      EBLK(q12, q13, q14, q15, w0, w1, w2, w3);
    }
    float dotf = (v0 + v1) + (v2 + v3);
    float s  = x2j + x2[b * MM + c];
    float tm = 2.0f * dotf;
    float d2 = s - tm;

    bool lt = (d2 < e15) || (d2 == e15 && c < n15);
    e15 = lt ? d2 : e15;
    n15 = lt ? c : n15;
    LBSTEP(e14, n14, e15, n15); LBSTEP(e13, n13, e14, n14);
    LBSTEP(e12, n12, e13, n13); LBSTEP(e11, n11, e12, n12);
    LBSTEP(e10, n10, e11, n11); LBSTEP(e9,  n9,  e10, n10);
    LBSTEP(e8,  n8,  e9,  n9);  LBSTEP(e7,  n7,  e8,  n8);
    LBSTEP(e6,  n6,  e7,  n7);  LBSTEP(e5,  n5,  e6,  n6);
    LBSTEP(e4,  n4,  e5,  n5);  LBSTEP(e3,  n3,  e4,  n4);
    LBSTEP(e2,  n2,  e3,  n3);  LBSTEP(e1,  n1,  e2,  n2);
    LBSTEP(e0,  n0,  e1,  n1);
  }

  // Publish sorted local lists as (mono key, idx).
#define MONO(F) ({ int k_ = __float_as_int(F); \
                   (unsigned)k_ ^ ((unsigned)(k_ >> 31) | 0x80000000u); })
  ls[sub][0][lane]  = make_uint2(MONO(e0),  (unsigned)n0);
  ls[sub][1][lane]  = make_uint2(MONO(e1),  (unsigned)n1);
  ls[sub][2][lane]  = make_uint2(MONO(e2),  (unsigned)n2);
  ls[sub][3][lane]  = make_uint2(MONO(e3),  (unsigned)n3);
  ls[sub][4][lane]  = make_uint2(MONO(e4),  (unsigned)n4);
  ls[sub][5][lane]  = make_uint2(MONO(e5),  (unsigned)n5);
  ls[sub][6][lane]  = make_uint2(MONO(e6),  (unsigned)n6);
  ls[sub][7][lane]  = make_uint2(MONO(e7),  (unsigned)n7);
  ls[sub][8][lane]  = make_uint2(MONO(e8),  (unsigned)n8);
  ls[sub][9][lane]  = make_uint2(MONO(e9),  (unsigned)n9);
  ls[sub][10][lane] = make_uint2(MONO(e10), (unsigned)n10);
  ls[sub][11][lane] = make_uint2(MONO(e11), (unsigned)n11);
  ls[sub][12][lane] = make_uint2(MONO(e12), (unsigned)n12);
  ls[sub][13][lane] = make_uint2(MONO(e13), (unsigned)n13);
  ls[sub][14][lane] = make_uint2(MONO(e14), (unsigned)n14);
  ls[sub][15][lane] = make_uint2(MONO(e15), (unsigned)n15);
#undef MONO
  __syncthreads();

  if (sub == 0) {
    uint2 c0v = ls[0][0][lane];
    uint2 c1v = ls[1][0][lane];
    uint2 c2v = ls[2][0][lane];
    uint2 c3v = ls[3][0][lane];
    int h0 = 1, h1 = 1, h2 = 1, h3 = 1;
    const uint2 SENT = make_uint2(0xFFFFFFFFu, 0x7FFFFFFFu);
#define LESS2(A, B) ((A).x < (B).x || ((A).x == (B).x && (A).y < (B).y))
    for (int out = 0; out < KK; ++out) {
      bool l01 = LESS2(c0v, c1v);
      uint2 m01 = l01 ? c0v : c1v;
      int  w01 = l01 ? 0 : 1;
      bool l23 = LESS2(c2v, c3v);
      uint2 m23 = l23 ? c2v : c3v;
      int  w23 = l23 ? 2 : 3;
      bool lf = LESS2(m01, m23);
      uint2 mv = lf ? m01 : m23;
      int  wf = lf ? w01 : w23;

      src[(size_t)r * KK + out] = b * MM + (int)mv.y;
      dst[(size_t)r * KK + out] = r;

      if (wf == 0) { c0v = (h0 < 16) ? ls[0][h0][lane] : SENT; ++h0; }
      else if (wf == 1) { c1v = (h1 < 16) ? ls[1][h1][lane] : SENT; ++h1; }
      else if (wf == 2) { c2v = (h2 < 16) ? ls[2][h2][lane] : SENT; ++h2; }
      else              { c3v = (h3 < 16) ? ls[3][h3][lane] : SENT; ++h3; }
    }
#undef LESS2
  }
}

template <int P, bool Q2>
static void launch_all(const float* x, int* out, void* d_ws, hipStream_t stream) {
  char* ws = (char*)d_ws;
  float* x2 = (float*)ws;
  int*   pi = (int*)(ws + (size_t)NROWS * sizeof(float));

  int* src = out;
  int* dst = out + (size_t)NROWS * KK;

  norms_np_kernel<<<NROWS / 256, 256, 0, stream>>>(x, x2);
  if (Q2) {
    knn_partial2_kernel<P><<<(NROWS / 512) * P, 256, 0, stream>>>(x, x2, pi);
  } else {
    knn_partial_q1_kernel<P><<<(NROWS / 256) * P, 256, 0, stream>>>(x, x2, pi);
  }
  knn_rescore4_kernel<P><<<NROWS / 64, 256, 0, stream>>>(x, x2, pi, src, dst);
}

extern "C" void kernel_launch(void* const* d_in, const int* in_sizes, int n_in,
                              void* d_out, int out_size, void* d_ws, size_t ws_size,
                              hipStream_t stream) {
  const float* x = (const float*)d_in[0];
  int* out = (int*)d_out;

  auto need = [](int P) {
    return (size_t)NROWS * sizeof(float) +
           (size_t)NROWS * P * TK * sizeof(int);
  };

  if (ws_size >= need(8)) {
    launch_all<8, true>(x, out, d_ws, stream);   // Q=2 no-LDS, P=8
  } else if (ws_size >= need(4)) {
    launch_all<4, true>(x, out, d_ws, stream);   // Q=2 no-LDS, P=4
  } else if (ws_size >= need(2)) {
    launch_all<2, false>(x, out, d_ws, stream);
  } else {
    launch_all<1, false>(x, out, d_ws, stream);
  }
}